// Round 10
// baseline (72.619 us; speedup 1.0000x reference)
//
#include <hip/hip_runtime.h>

#define BATCH   256
#define NCOL    576
#define MROW    144
#define ZLIFT   24
#define NIT     3
#define ROW_DEG 15
#define PKSTR   16                               // pk row stride (int4-friendly)
#define NSCIT   ((MROW/ZLIFT) * (NCOL/ZLIFT) * NIT)  // 432
#define TPB     576                              // 9 waves; == NCOL == 4*MROW

// Kernel 1: one wave per check row. int4 loads + 4-ballot rank computation;
// ascending column order preserved (argmin tie-break needs it).
// Packs n | (sidx*3)<<16 (sidx=(m/24)*24+n/24, pre-multiplied by NIT) at row
// stride PKSTR=16. Entry 15 is a sentinel (0) so decode can int4-load it.
__global__ __launch_bounds__(256) void build_cols_kernel(
    const int* __restrict__ H, int* __restrict__ pk)
{
    const int wave = (blockIdx.x * blockDim.x + threadIdx.x) >> 6;
    const int lane = threadIdx.x & 63;
    if (wave >= MROW) return;
    const int4* row4 = (const int4*)(H + (size_t)wave * NCOL);
    const int srow = (wave / ZLIFT) * (NCOL / ZLIFT);
    const unsigned long long below = (1ull << lane) - 1ull;
    if (lane == 0) pk[wave * PKSTR + 15] = 0;   // sentinel pad entry
    int base = 0;
    #pragma unroll
    for (int r0 = 0; r0 < 3; ++r0) {
        const int vidx = r0 * 64 + lane;        // int4 index within row, 0..143
        int4 h = make_int4(0, 0, 0, 0);
        if (vidx < NCOL / 4) h = row4[vidx];
        const int b0 = h.x != 0, b1 = h.y != 0, b2 = h.z != 0, b3 = h.w != 0;
        const unsigned long long m0 = __ballot(b0);
        const unsigned long long m1 = __ballot(b1);
        const unsigned long long m2 = __ballot(b2);
        const unsigned long long m3 = __ballot(b3);
        const int cnt_below = __popcll(m0 & below) + __popcll(m1 & below)
                            + __popcll(m2 & below) + __popcll(m3 & below);
        const int bits[4] = {b0, b1, b2, b3};
        const int n0 = vidx * 4;
        int pref = 0;
        #pragma unroll
        for (int c = 0; c < 4; ++c) {
            if (bits[c]) {
                const int idx = base + cnt_below + pref;
                const int n = n0 + c;
                if (idx < ROW_DEG)
                    pk[wave * PKSTR + idx] = n | (((srow + n / ZLIFT) * NIT) << 16);
                ++pref;
            }
        }
        base += __popcll(m0) + __popcll(m1) + __popcll(m2) + __popcll(m3);
    }
}

// Kernel 2: one block (576 threads, 9 waves) per frame; TPB == NCOL.
// Each check row is owned by 4 ADJACENT LANES (row = tid>>2, sub = tid&3);
// lane sub handles edges [4*sub, 4*sub+4) (sub 3: 3 real + 1 sentinel).
// min-2/argmin/sign-product merged with 2 order-aware __shfl_xor steps
// (preserves top_k first-occurrence tie-break).
// Column sums accumulate DIRECTLY via LDS atomicAdd at E-write time into
// one of three single-use buffers (cs1 -> cs0 -> cs2, all zeroed at setup):
// no E array, no gather phase, no rank pass — 4 barriers total.
__global__ __launch_bounds__(TPB) void ldpc_decode_kernel(
    const float* __restrict__ r,
    const float* __restrict__ alpha,
    const float* __restrict__ beta,
    const int*   __restrict__ pk,
    float*       __restrict__ out)
{
    __shared__ float  r_s[NCOL];
    __shared__ float  cs0[NCOL];
    __shared__ float  cs1[NCOL];
    __shared__ float  cs2[NCOL];
    __shared__ float2 ab_s[NSCIT];        // interleaved {alpha, beta}

    const int b   = blockIdx.x;
    const int tid = threadIdx.x;
    const int row = tid >> 2;
    const int sub = tid & 3;

    // ---- setup: stage inputs, zero all colsum buffers (tid == column id) ----
    r_s[tid] = r[(size_t)b * NCOL + tid];
    cs0[tid] = 0.0f;
    cs1[tid] = 0.0f;
    cs2[tid] = 0.0f;
    if (tid < NSCIT) ab_s[tid] = make_float2(alpha[tid], beta[tid]);
    __syncthreads();   // B1

    // ---- per-lane edge state (<=4 edges), one aligned int4 of pk ----
    const int4 q = *(const int4*)(pk + row * PKSTR + sub * 4);
    int   pk_r[4] = {q.x, q.y, q.z, q.w};
    float r_r[4], E_r[4] = {0.0f, 0.0f, 0.0f, 0.0f};
    #pragma unroll
    for (int j = 0; j < 4; ++j)
        r_r[j] = r_s[pk_r[j] & 0xFFFF];   // sentinel reads r_s[0]: safe, unused

    // Check-node phase: M = r (+ prevsum - E_prev) on the fly; min-2 with
    // strict < (== top_k first-occurrence tie-break); extrinsic sign product;
    // E accumulated straight into `next` via ds_add_f32.
    auto check = [&](const float* prev, float* next, const int it) {
        float vals[4];
        float min1 = INFINITY, min2 = INFINITY;
        int   kmin = 1 << 30;
        float sprod = 1.0f;
        #pragma unroll
        for (int j = 0; j < 4; ++j) {
            const int kglob = sub * 4 + j;
            const bool val = (kglob < ROW_DEG);
            float v = r_r[j];
            if (prev) v += prev[pk_r[j] & 0xFFFF] - E_r[j];
            vals[j] = v;
            const float av = val ? fabsf(v) : INFINITY;
            const float s = val ? ((v > 0.0f) ? 1.0f : ((v < 0.0f) ? -1.0f : 0.0f))
                                : 1.0f;
            sprod *= s;
            if (av < min1)      { min2 = min1; min1 = av; kmin = kglob; }
            else if (av < min2) { min2 = av; }
        }
        // Order-aware merge across the 4 sub-lanes (lower-k side wins ties).
        #pragma unroll
        for (int m = 1; m <= 2; m <<= 1) {
            const float o1 = __shfl_xor(min1, m);
            const float o2 = __shfl_xor(min2, m);
            const int   ok = __shfl_xor(kmin, m);
            const float os = __shfl_xor(sprod, m);
            const bool self_lo = ((sub & m) == 0);
            const float lo1 = self_lo ? min1 : o1;
            const float lo2 = self_lo ? min2 : o2;
            const int   lok = self_lo ? kmin : ok;
            const float hi1 = self_lo ? o1 : min1;
            const float hi2 = self_lo ? o2 : min2;
            const int   hik = self_lo ? ok : kmin;
            if (hi1 < lo1) { min1 = hi1; kmin = hik; min2 = fminf(hi2, lo1); }
            else           { min1 = lo1; kmin = lok; min2 = fminf(lo2, hi1); }
            sprod *= os;
        }
        // Extrinsic messages for own edges -> atomic column accumulation.
        #pragma unroll
        for (int j = 0; j < 4; ++j) {
            const int kglob = sub * 4 + j;
            if (kglob < ROW_DEG) {
                const float v = vals[j];
                const float s = (v > 0.0f) ? 1.0f : ((v < 0.0f) ? -1.0f : 0.0f);
                const float2 ab = ab_s[(pk_r[j] >> 16) + it];
                const float eabs = (kglob == kmin) ? min2 : min1;
                float mag = eabs - ab.y;
                if (mag < 0.0f) mag = 0.0f;
                const float E = ab.x * (sprod * s) * mag;
                E_r[j] = E;
                atomicAdd(&next[pk_r[j] & 0xFFFF], E);
            }
        }
    };

    check(nullptr, cs1, 0);
    __syncthreads();   // B2: cs1 complete
    check(cs1, cs0, 1);
    __syncthreads();   // B3: cs0 complete
    check(cs0, cs2, 2);
    __syncthreads();   // B4: cs2 complete

    out[(size_t)b * NCOL + tid] = r_s[tid] + cs2[tid];
}

extern "C" void kernel_launch(void* const* d_in, const int* in_sizes, int n_in,
                              void* d_out, int out_size, void* d_ws, size_t ws_size,
                              hipStream_t stream) {
    const float* r     = (const float*)d_in[0];
    const float* alpha = (const float*)d_in[1];
    const float* beta  = (const float*)d_in[2];
    const int*   H     = (const int*)d_in[3];
    float* out = (float*)d_out;
    int*   pk  = (int*)d_ws;   // MROW*PKSTR packed ints

    build_cols_kernel<<<(MROW * 64 + 255) / 256, 256, 0, stream>>>(H, pk);
    ldpc_decode_kernel<<<BATCH, TPB, 0, stream>>>(r, alpha, beta, pk, out);
}

// Round 11
// 65.363 us; speedup vs baseline: 1.1110x; 1.1110x over previous
//
#include <hip/hip_runtime.h>

#define BATCH   256
#define NCOL    576
#define MROW    144
#define ZLIFT   24
#define NIT     3
#define ROW_DEG 15
#define PKSTR   16                               // pk row stride (int4-friendly)
#define NSCIT   ((MROW/ZLIFT) * (NCOL/ZLIFT) * NIT)  // 432
#define TPB     576                              // 9 waves; == NCOL == 4*MROW
#define CCAP    17   // max column degree <= 17 (proven: R3 cap-17 == R4 exact, bit-identical)
#define CSTR    19   // padded stride, odd -> LDS bank period 32 (conflict-free)

// Kernel 1: one wave per check row. int4 loads + 4-ballot rank computation;
// ascending column order preserved (argmin tie-break needs it).
// Packs n | ((sidx*NIT)<<16), sidx=(m/24)*24+n/24, at row stride PKSTR=16.
// Entry 15 of each row is a sentinel (0) so decode can safely int4-load it.
__global__ __launch_bounds__(256) void build_cols_kernel(
    const int* __restrict__ H, int* __restrict__ pk)
{
    const int wave = (blockIdx.x * blockDim.x + threadIdx.x) >> 6;
    const int lane = threadIdx.x & 63;
    if (wave >= MROW) return;
    const int4* row4 = (const int4*)(H + (size_t)wave * NCOL);
    const int srow = (wave / ZLIFT) * (NCOL / ZLIFT);
    const unsigned long long below = (1ull << lane) - 1ull;
    if (lane == 0) pk[wave * PKSTR + 15] = 0;   // sentinel pad entry
    int base = 0;
    #pragma unroll
    for (int r0 = 0; r0 < 3; ++r0) {
        const int vidx = r0 * 64 + lane;        // int4 index within row, 0..143
        int4 h = make_int4(0, 0, 0, 0);
        if (vidx < NCOL / 4) h = row4[vidx];
        const int b0 = h.x != 0, b1 = h.y != 0, b2 = h.z != 0, b3 = h.w != 0;
        const unsigned long long m0 = __ballot(b0);
        const unsigned long long m1 = __ballot(b1);
        const unsigned long long m2 = __ballot(b2);
        const unsigned long long m3 = __ballot(b3);
        const int cnt_below = __popcll(m0 & below) + __popcll(m1 & below)
                            + __popcll(m2 & below) + __popcll(m3 & below);
        const int bits[4] = {b0, b1, b2, b3};
        const int n0 = vidx * 4;
        int pref = 0;
        #pragma unroll
        for (int c = 0; c < 4; ++c) {
            if (bits[c]) {
                const int idx = base + cnt_below + pref;
                const int n = n0 + c;
                if (idx < ROW_DEG)
                    pk[wave * PKSTR + idx] = n | (((srow + n / ZLIFT) * NIT) << 16);
                ++pref;
            }
        }
        base += __popcll(m0) + __popcll(m1) + __popcll(m2) + __popcll(m3);
    }
}

// Kernel 2: one block (576 threads, 9 waves) per frame; TPB == NCOL.
// Each check row is owned by 4 ADJACENT LANES (row = tid>>2, sub = tid&3);
// lane sub handles edges k in [4*sub, 4*sub+4) (sub 3: 3 real + 1 sentinel).
// Partial min-2/argmin/sign-product merged with 2 order-aware __shfl_xor
// steps (preserves top_k first-occurrence tie-break) — no extra barriers.
// E messages live in fixed-stride padded column layout (CSTR=19, CCAP=17):
// slot = n*19 + atomic rank; pads stay 0.0f so the gather is a fully
// unrolled 17-read sum, one column per thread. (NO LDS fp atomics for the
// sum itself — R10 showed ds fp-atomic serialization loses to independent
// reads.)
__global__ __launch_bounds__(TPB) void ldpc_decode_kernel(
    const float* __restrict__ r,
    const float* __restrict__ alpha,
    const float* __restrict__ beta,
    const int*   __restrict__ pk,
    float*       __restrict__ out)
{
    __shared__ float  r_s[NCOL];
    __shared__ float  colsum[NCOL];
    __shared__ float  E_s[NCOL * CSTR];   // 10944 floats = 43.8 KB
    __shared__ float2 ab_s[NSCIT];        // interleaved {alpha, beta}
    __shared__ int    cdeg[NCOL];         // atomic rank counters

    const int b   = blockIdx.x;
    const int tid = threadIdx.x;
    const int row = tid >> 2;
    const int sub = tid & 3;

    // Issue ALL global loads first so HBM/L2 latency overlaps the LDS setup
    // and the barrier (pk load hoisted above B1 — it has no LDS dependence).
    const int4  q  = *(const int4*)(pk + row * PKSTR + sub * 4);
    const float rv = r[(size_t)b * NCOL + tid];
    float2 abv;
    if (tid < NSCIT) abv = make_float2(alpha[tid], beta[tid]);

    // ---- setup: stage inputs, zero E + rank counters (tid == column id) ----
    r_s[tid]  = rv;
    cdeg[tid] = 0;
    #pragma unroll
    for (int j = 0; j < CSTR; ++j) E_s[j * NCOL + tid] = 0.0f;
    if (tid < NSCIT) ab_s[tid] = abv;
    __syncthreads();   // B1: staged + zeroed

    // ---- per-lane edge state (<=4 edges) ----
    int pk_r[4] = {q.x, q.y, q.z, q.w};
    float r_r[4], E_r[4];
    int   slot_r[4];
    #pragma unroll
    for (int j = 0; j < 4; ++j) {
        const int kglob = sub * 4 + j;
        const int n = pk_r[j] & 0xFFFF;
        r_r[j] = r_s[n];               // sentinel reads r_s[0]: safe, unused
        E_r[j] = 0.0f;
        if (kglob < ROW_DEG)
            slot_r[j] = n * CSTR + atomicAdd(&cdeg[n], 1);
    }
    // (no barrier: slots register-private; E_s zero completed before B1)

    // ---- iterations ----
    for (int it = 0; it < NIT; ++it) {
        // Check phase: partial scan over own edges, then 2-step shuffle merge.
        float vals[4];
        float min1 = INFINITY, min2 = INFINITY;
        int   kmin = 1 << 30;
        float sprod = 1.0f;
        #pragma unroll
        for (int j = 0; j < 4; ++j) {
            const int kglob = sub * 4 + j;
            const bool val = (kglob < ROW_DEG);
            float v;
            if (it == 0) {
                v = r_r[j];
            } else {
                const int n = pk_r[j] & 0xFFFF;
                v = r_r[j] + colsum[n] - E_r[j];
            }
            vals[j] = v;
            const float av = val ? fabsf(v) : INFINITY;
            const float s = val ? ((v > 0.0f) ? 1.0f : ((v < 0.0f) ? -1.0f : 0.0f))
                                : 1.0f;
            sprod *= s;
            if (av < min1)      { min2 = min1; min1 = av; kmin = kglob; }
            else if (av < min2) { min2 = av; }
        }
        // Order-aware merge across the 4 sub-lanes (lower-k side wins ties ==
        // top_k first-occurrence).
        #pragma unroll
        for (int m = 1; m <= 2; m <<= 1) {
            const float o1 = __shfl_xor(min1, m);
            const float o2 = __shfl_xor(min2, m);
            const int   ok = __shfl_xor(kmin, m);
            const float os = __shfl_xor(sprod, m);
            const bool self_lo = ((sub & m) == 0);
            const float lo1 = self_lo ? min1 : o1;
            const float lo2 = self_lo ? min2 : o2;
            const int   lok = self_lo ? kmin : ok;
            const float hi1 = self_lo ? o1 : min1;
            const float hi2 = self_lo ? o2 : min2;
            const int   hik = self_lo ? ok : kmin;
            if (hi1 < lo1) { min1 = hi1; kmin = hik; min2 = fminf(hi2, lo1); }
            else           { min1 = lo1; kmin = lok; min2 = fminf(lo2, hi1); }
            sprod *= os;
        }
        // Extrinsic messages for own edges.
        #pragma unroll
        for (int j = 0; j < 4; ++j) {
            const int kglob = sub * 4 + j;
            if (kglob < ROW_DEG) {
                const float v = vals[j];
                const float s = (v > 0.0f) ? 1.0f : ((v < 0.0f) ? -1.0f : 0.0f);
                const float2 ab = ab_s[(pk_r[j] >> 16) + it];
                const float eabs = (kglob == kmin) ? min2 : min1;
                float mag = eabs - ab.y;
                if (mag < 0.0f) mag = 0.0f;
                const float E = ab.x * (sprod * s) * mag;
                E_r[j] = E;
                E_s[slot_r[j]] = E;
            }
        }
        __syncthreads();   // E_s complete; colsum reads done

        // Variable-node phase: one column per thread, fixed 17-read sum
        // (pads are exactly +0.0f). Last iteration fused into output write.
        const float* base = &E_s[tid * CSTR];
        float sum = 0.0f;
        #pragma unroll
        for (int i = 0; i < CCAP; ++i) sum += base[i];
        if (it < NIT - 1) {
            colsum[tid] = sum;
            __syncthreads();   // colsum complete before next check phase
        } else {
            out[(size_t)b * NCOL + tid] = r_s[tid] + sum;
        }
    }
}

extern "C" void kernel_launch(void* const* d_in, const int* in_sizes, int n_in,
                              void* d_out, int out_size, void* d_ws, size_t ws_size,
                              hipStream_t stream) {
    const float* r     = (const float*)d_in[0];
    const float* alpha = (const float*)d_in[1];
    const float* beta  = (const float*)d_in[2];
    const int*   H     = (const int*)d_in[3];
    float* out = (float*)d_out;
    int*   pk  = (int*)d_ws;   // MROW*PKSTR packed ints

    build_cols_kernel<<<(MROW * 64 + 255) / 256, 256, 0, stream>>>(H, pk);
    ldpc_decode_kernel<<<BATCH, TPB, 0, stream>>>(r, alpha, beta, pk, out);
}